// Round 9
// baseline (188.327 us; speedup 1.0000x reference)
//
#include <hip/hip_runtime.h>
#include <hip/hip_bf16.h>
#include <math.h>

#define BDIM 4
#define SLEN 4096
#define DDIM 1024
#define MROWS (BDIM*SLEN)      // 16384
#define KDIM DDIM              // 1024
#define NCHUNK 64
#define CLEN (SLEN/NCHUNK)     // 64
#define NCH (BDIM*DDIM)        // 4096
#define NKT (KDIM/32)          // 32 K-steps
#define GBUF 16384             // one LDS buffer: X 8KB (4 tiles) + W 8KB (4 tiles)

typedef __bf16 bf16;
typedef __bf16 bf16x8 __attribute__((ext_vector_type(8)));
typedef float f32x4 __attribute__((ext_vector_type(4)));

__device__ __forceinline__ void gload_lds16(const void* g, void* l) {
  __builtin_amdgcn_global_load_lds(
      (const __attribute__((address_space(1))) unsigned int*)g,
      (__attribute__((address_space(3))) unsigned int*)l, 16, 0, 0);
}

// ---------------- cast f32 -> bf16, fragment-order for 16x16x32 frags -------
// Tile = 32 rows x 32 k (2KB) at [T][KT]. Within tile, HALF-tile = 16 rows:
// granule (row r, k-gran j) stored at slot (r>>4)*64 + j*16 + (r&15).
// A 16x16x32 fragment read (rows r0..r0+15, k 0..31) is then base + lane*16:
// lane l -> slot j=(l>>4), rr=(l&15)  => linear, conflict-free.
// Reads stay coalesced (4-lane clusters read 64B contiguous per row).
__global__ void cast_swz_kernel(const float* __restrict__ in, bf16* __restrict__ out) {
  const int gid  = blockIdx.x * 256 + threadIdx.x;
  const int tile = gid >> 7, local = gid & 127;
  const int j = local & 3, r = local >> 2;     // coalesced read assignment
  const int T = tile >> 5, KT = tile & 31;
  const float4* src = (const float4*)(in + (size_t)(T*32 + r) * KDIM + KT*32 + j*8);
  float4 v0 = src[0], v1 = src[1];
  bf16x8 o;
  o[0] = (bf16)v0.x; o[1] = (bf16)v0.y; o[2] = (bf16)v0.z; o[3] = (bf16)v0.w;
  o[4] = (bf16)v1.x; o[5] = (bf16)v1.y; o[6] = (bf16)v1.z; o[7] = (bf16)v1.w;
  ((bf16x8*)out)[(size_t)tile * 128 + ((r >> 4) * 64 + j * 16 + (r & 15))] = o;
}

// ---------------- klam[h] = -C * softplus(-Lam[h]) ----------------
__global__ void klam_kernel(const float* __restrict__ Lam, float* __restrict__ klam) {
  int h = blockIdx.x * blockDim.x + threadIdx.x;
  if (h < DDIM) klam[h] = -8.0f * log1pf(__expf(-Lam[h]));
}

// ---------------- single-weight GEMM + gate epilogue ----------------
// m97-exact wave tile: 128x128 block, 4 waves (2x2), per-wave 64x64,
// 16x16x32 MFMA, 8 ds_read : 16 MFMA per K-step, acc = 16 f32x4 (64 regs).
// 2-buffer LDS (32KB) -> 4 blocks/CU; __launch_bounds__(256,4) -> 4 waves/SIMD.
// GATE=0: out = a = exp(klam*sigmoid(Ga+ba))
// GATE=1: out = b' = sigmoid(Gx+bx)*x     (sqrt(1-a^2) folded into scans)
template<int GATE>
__global__ __launch_bounds__(256, 4) void gemm_gate_kernel(
    const bf16* __restrict__ xb, const bf16* __restrict__ wb,
    const float* __restrict__ bias, const float* __restrict__ klam,
    float* __restrict__ outp)
{
  __shared__ char smem[2*GBUF];

  const int tid  = threadIdx.x;
  const int wave = tid >> 6, lane = tid & 63;
  const int wm = wave >> 1, wn = wave & 1;       // 2x2 waves, 64x64 each

  // XCD-bijective swizzle: 1024 blocks, 8 XCDs, 128 each.
  const int orig  = blockIdx.x;
  const int newid = (orig & 7) * 128 + (orig >> 3);
  const int m0 = (newid >> 3) * 128;
  const int h0 = (newid & 7) * 128;

  f32x4 acc[4][4];
  #pragma unroll
  for (int i = 0; i < 4; i++)
    #pragma unroll
    for (int j = 0; j < 4; j++) acc[i][j] = (f32x4)0.0f;

  // staging: thread t stages granule (t&127) of row-tile (t>>7) pair
  const int g  = (tid & 127) * 8;
  const int i2 = tid >> 7;
  const int Tb = m0 >> 5, Hb = h0 >> 5;
  const bf16* xsrc0 = xb + (size_t)(Tb + i2)     * 32768 + g;
  const bf16* xsrc1 = xb + (size_t)(Tb + 2 + i2) * 32768 + g;
  const bf16* wsrc0 = wb + (size_t)(Hb + i2)     * 32768 + g;
  const bf16* wsrc1 = wb + (size_t)(Hb + 2 + i2) * 32768 + g;

  auto STAGE = [&](int kt, char* nb) {
    const int ko = kt * 1024;
    gload_lds16(xsrc0 + ko, nb + tid*16);            // X tiles 0,1
    gload_lds16(xsrc1 + ko, nb + 4096  + tid*16);    // X tiles 2,3
    gload_lds16(wsrc0 + ko, nb + 8192  + tid*16);    // W tiles 0,1
    gload_lds16(wsrc1 + ko, nb + 12288 + tid*16);    // W tiles 2,3
  };

  char* pc = smem;
  char* pn = smem + GBUF;

  STAGE(0, pc);

  for (int kt = 0; kt < NKT; ++kt) {
    asm volatile("s_waitcnt vmcnt(0)" ::: "memory");   // tile kt landed
    __builtin_amdgcn_s_barrier();                      // all waves done reading pn(kt-1)
    __builtin_amdgcn_sched_barrier(0);

    if (kt + 1 < NKT) STAGE(kt + 1, pn);               // safe: post-barrier

    bf16x8 af[4], bfr[4];
    #pragma unroll
    for (int mi = 0; mi < 4; mi++)
      af[mi] = *(const bf16x8*)(pc + (wm*2 + (mi>>1))*2048 + (mi&1)*1024 + lane*16);
    #pragma unroll
    for (int ni = 0; ni < 4; ni++)
      bfr[ni] = *(const bf16x8*)(pc + 8192 + (wn*2 + (ni>>1))*2048 + (ni&1)*1024 + lane*16);

    __builtin_amdgcn_s_setprio(1);
    #pragma unroll
    for (int mi = 0; mi < 4; mi++)
      #pragma unroll
      for (int ni = 0; ni < 4; ni++)
        acc[mi][ni] = __builtin_amdgcn_mfma_f32_16x16x32_bf16(af[mi], bfr[ni], acc[mi][ni], 0, 0, 0);
    __builtin_amdgcn_s_setprio(0);

    char* t = pc; pc = pn; pn = t;
  }

  // epilogue: C/D layout col = lane&15 (h), row = (lane>>4)*4 + j (m)
  #pragma unroll
  for (int ni = 0; ni < 4; ni++) {
    const int h = h0 + wn*64 + ni*16 + (lane & 15);
    const float bh = bias[h];
    const float kl = (GATE == 0) ? klam[h] : 0.0f;
    #pragma unroll
    for (int mi = 0; mi < 4; mi++) {
      const int mb = m0 + wm*64 + mi*16 + ((lane >> 4) << 2);
      #pragma unroll
      for (int j = 0; j < 4; j++) {
        const int m = mb + j;
        const float gg = acc[mi][ni][j] + bh;
        const float sg = 1.0f / (1.0f + __expf(-gg));
        float v;
        if (GATE == 0) {
          v = __expf(kl * sg);                 // a
        } else {
          // x reload from fragment-order xb: slot = (m&16?64:0)+j16*16+(m&15)
          const size_t e = (size_t)((m >> 5) * 32 + (h >> 5)) * 1024
                         + (size_t)(((m >> 4) & 1) * 64 + ((h >> 3) & 3) * 16 + (m & 15)) * 8
                         + (h & 7);
          v = sg * (float)xb[e];               // b' = it * x
        }
        outp[(size_t)m * DDIM + h] = v;
      }
    }
  }
}

// ---------------- chunked scan: phase 1 (per-chunk summaries) ----------------
// b = sqrt(1-a^2) * b'   (fold from gemm epilogue split)
__global__ void scan1_kernel(const float* __restrict__ Aarr, const float* __restrict__ Bp,
                             float* __restrict__ sA, float* __restrict__ sB) {
  const int ch = blockIdx.x * 256 + threadIdx.x;   // 0..4095 = b*1024 + d
  const int c  = blockIdx.y;                       // chunk
  const int b  = ch >> 10, d = ch & 1023;
  size_t idx = ((size_t)b * SLEN + (size_t)c * CLEN) * DDIM + d;
  float pa = 1.0f, h = 0.0f;
  #pragma unroll 4
  for (int s = 0; s < CLEN; ++s) {
    const float a  = Aarr[idx];
    const float bb = sqrtf(fmaxf(1.0f - a*a, 0.0f)) * Bp[idx];
    h  = fmaf(a, h, bb);
    pa *= a;
    idx += DDIM;
  }
  sA[c * NCH + ch] = pa;
  sB[c * NCH + ch] = h;
}

// ---------------- phase 2: sequential prefix over chunks ----------------
__global__ void scan2_kernel(const float* __restrict__ sA, const float* __restrict__ sB,
                             float* __restrict__ Hin) {
  const int ch = blockIdx.x * 256 + threadIdx.x;
  float h = 0.0f;
  for (int c = 0; c < NCHUNK; ++c) {
    Hin[c * NCH + ch] = h;
    h = fmaf(sA[c * NCH + ch], h, sB[c * NCH + ch]);
  }
}

// ---------------- phase 3: apply (in place over b' == d_out) ----------------
__global__ void scan3_kernel(const float* __restrict__ Aarr, const float* __restrict__ Hin,
                             float* __restrict__ y) {
  const int ch = blockIdx.x * 256 + threadIdx.x;
  const int c  = blockIdx.y;
  const int b  = ch >> 10, d = ch & 1023;
  size_t idx = ((size_t)b * SLEN + (size_t)c * CLEN) * DDIM + d;
  float h = Hin[c * NCH + ch];
  #pragma unroll 4
  for (int s = 0; s < CLEN; ++s) {
    const float a  = Aarr[idx];
    const float bb = sqrtf(fmaxf(1.0f - a*a, 0.0f)) * y[idx];
    h = fmaf(a, h, bb);
    y[idx] = h;
    idx += DDIM;
  }
}

extern "C" void kernel_launch(void* const* d_in, const int* in_sizes, int n_in,
                              void* d_out, int out_size, void* d_ws, size_t ws_size,
                              hipStream_t stream) {
  const float* x   = (const float*)d_in[0];
  const float* Wa  = (const float*)d_in[1];
  const float* Wx  = (const float*)d_in[2];
  const float* ba  = (const float*)d_in[3];
  const float* bx  = (const float*)d_in[4];
  const float* Lam = (const float*)d_in[5];
  float* y = (float*)d_out;

  // workspace layout (bytes): needs 108,007,424 total
  if (ws_size < 108007424ULL) return;  // insufficient scratch; fail cleanly
  char* ws = (char*)d_ws;
  float* Aarr = (float*)(ws);                    // 64 MB: decay a
  bf16*  xb   = (bf16*)(ws + 67108864);          // 32 MB: x bf16, frag-order
  bf16*  wab  = (bf16*)(ws + 100663296);         //  2 MB, frag-order
  bf16*  wxb  = (bf16*)(ws + 102760448);         //  2 MB, frag-order
  float* klam = (float*)(ws + 104857600);        //  4 KB
  float* sA   = (float*)(ws + 104861696);        //  1 MB
  float* sB   = (float*)(ws + 105910272);        //  1 MB
  float* Hin  = (float*)(ws + 106958848);        //  1 MB
  float* Bprime = y;                             // b' lives in d_out, transformed in place

  cast_swz_kernel<<<(MROWS/32)*(KDIM/32)*128/256, 256, 0, stream>>>(x,  xb);
  cast_swz_kernel<<<(DDIM/32)*(KDIM/32)*128/256, 256, 0, stream>>>(Wa, wab);
  cast_swz_kernel<<<(DDIM/32)*(KDIM/32)*128/256, 256, 0, stream>>>(Wx, wxb);
  klam_kernel<<<DDIM/256, 256, 0, stream>>>(Lam, klam);

  // 1024 blocks each: (M/128) * (N/128) = 128 * 8
  gemm_gate_kernel<0><<<1024, 256, 0, stream>>>(xb, wab, ba, klam, Aarr);
  gemm_gate_kernel<1><<<1024, 256, 0, stream>>>(xb, wxb, bx, klam, Bprime);

  dim3 sgrid(NCH/256, NCHUNK);
  scan1_kernel<<<sgrid, 256, 0, stream>>>(Aarr, Bprime, sA, sB);
  scan2_kernel<<<NCH/256, 256, 0, stream>>>(sA, sB, Hin);
  scan3_kernel<<<sgrid, 256, 0, stream>>>(Aarr, Hin, y);
}

// Round 10
// 185.703 us; speedup vs baseline: 1.0141x; 1.0141x over previous
//
#include <hip/hip_runtime.h>
#include <hip/hip_bf16.h>
#include <math.h>

#define BDIM 4
#define SLEN 4096
#define DDIM 1024
#define MROWS (BDIM*SLEN)      // 16384
#define KDIM DDIM              // 1024
#define NCHUNK 64
#define CLEN (SLEN/NCHUNK)     // 64
#define NCH (BDIM*DDIM)        // 4096
#define NKT (KDIM/32)          // 32 K-steps

typedef __bf16 bf16;
typedef __bf16 bf16x8 __attribute__((ext_vector_type(8)));
typedef float f32x4 __attribute__((ext_vector_type(4)));

// ---------------- cast f32 -> bf16, fragment-order (16x16x32 frags) ---------
// Tile = 32 rows x 32 k (2KB) at [T][KT]. Granule (row r, k-gran j) stored at
// slot (r>>4)*64 + j*16 + (r&15). A 16x16 fragment (16 rows, k 0..31) is then
// elem = tile*1024 + half*512 + lane*8 : contiguous 1KB per wave. [R9-verified]
__global__ void cast_swz_kernel(const float* __restrict__ in, bf16* __restrict__ out) {
  const int gid  = blockIdx.x * 256 + threadIdx.x;
  const int tile = gid >> 7, local = gid & 127;
  const int j = local & 3, r = local >> 2;     // coalesced read assignment
  const int T = tile >> 5, KT = tile & 31;
  const float4* src = (const float4*)(in + (size_t)(T*32 + r) * KDIM + KT*32 + j*8);
  float4 v0 = src[0], v1 = src[1];
  bf16x8 o;
  o[0] = (bf16)v0.x; o[1] = (bf16)v0.y; o[2] = (bf16)v0.z; o[3] = (bf16)v0.w;
  o[4] = (bf16)v1.x; o[5] = (bf16)v1.y; o[6] = (bf16)v1.z; o[7] = (bf16)v1.w;
  ((bf16x8*)out)[(size_t)tile * 128 + ((r >> 4) * 64 + j * 16 + (r & 15))] = o;
}

// ---------------- klam[h] = -C * softplus(-Lam[h]) ----------------
__global__ void klam_kernel(const float* __restrict__ Lam, float* __restrict__ klam) {
  int h = blockIdx.x * blockDim.x + threadIdx.x;
  if (h < DDIM) klam[h] = -8.0f * log1pf(__expf(-Lam[h]));
}

#define MFMA_(A,B,C) C = __builtin_amdgcn_mfma_f32_16x16x32_bf16(A, B, C, 0, 0, 0)

// ---------------- LDS-free dual-weight GEMM + gate epilogue ----------------
// Block 128(M) x 64(N)-dual, 4 waves (2x2), per-wave 64m x 32n-dual.
// Fragments loaded global->VGPR directly from fragment-order arrays:
// per K-step per wave: 8 coalesced 1KB loads + 16 MFMA. NO LDS, NO barriers,
// no vmcnt(0) — compiler emits counted-vmcnt pipeline; waves free-run.
// 2-deep register double-buffer (static names), cover = 1 MFMA-step (~310cy).
__global__ __launch_bounds__(256, 3) void gemm_gates_kernel(
    const bf16* __restrict__ xb, const bf16* __restrict__ wab, const bf16* __restrict__ wxb,
    const float* __restrict__ ba, const float* __restrict__ bx,
    const float* __restrict__ klam, float* __restrict__ Aarr, bf16* __restrict__ Bp)
{
  const int tid  = threadIdx.x;
  const int wave = tid >> 6, lane = tid & 63;
  const int wm = wave >> 1, wn = wave & 1;       // M split 2x64, N split 2x32

  // XCD-bijective swizzle: 2048 blocks, 8 XCDs, 256 each (m-chunked -> X L2-res)
  const int orig  = blockIdx.x;
  const int newid = (orig & 7) * 256 + (orig >> 3);
  const int m0 = (newid >> 4) * 128;
  const int h0 = (newid & 15) * 64;

  f32x4 accA[4][2], accX[4][2];
  #pragma unroll
  for (int i = 0; i < 4; i++)
    #pragma unroll
    for (int j = 0; j < 2; j++) { accA[i][j] = (f32x4)0.0f; accX[i][j] = (f32x4)0.0f; }

  // fragment base addrs (frag-order global). Tile stride (T -> T+1) = 32768 elems.
  const bf16* aBase  = xb  + (size_t)((m0 + wm*64) >> 5) * 32768 + (size_t)lane * 8;
  const bf16* bBaseA = wab + (size_t)((h0 >> 5) + wn)    * 32768 + (size_t)lane * 8;
  const bf16* bBaseX = wxb + (size_t)((h0 >> 5) + wn)    * 32768 + (size_t)lane * 8;

  bf16x8 fa0[4], fb0[2], fx0[2];   // buffer 0 (even kt)
  bf16x8 fa1[4], fb1[2], fx1[2];   // buffer 1 (odd kt)

#define LOADF(FA, FB, FX, KT) do {                                   \
    const bf16* ap_ = aBase  + (size_t)(KT) * 1024;                  \
    FA[0] = *(const bf16x8*)(ap_);                                   \
    FA[1] = *(const bf16x8*)(ap_ + 512);                             \
    FA[2] = *(const bf16x8*)(ap_ + 32768);                           \
    FA[3] = *(const bf16x8*)(ap_ + 32768 + 512);                     \
    const bf16* bp_ = bBaseA + (size_t)(KT) * 1024;                  \
    FB[0] = *(const bf16x8*)(bp_);                                   \
    FB[1] = *(const bf16x8*)(bp_ + 512);                             \
    const bf16* xp_ = bBaseX + (size_t)(KT) * 1024;                  \
    FX[0] = *(const bf16x8*)(xp_);                                   \
    FX[1] = *(const bf16x8*)(xp_ + 512);                             \
  } while (0)

#define MSTEP(FA, FB, FX) do {                                       \
    MFMA_(FA[0], FB[0], accA[0][0]); MFMA_(FA[0], FB[1], accA[0][1]);\
    MFMA_(FA[0], FX[0], accX[0][0]); MFMA_(FA[0], FX[1], accX[0][1]);\
    MFMA_(FA[1], FB[0], accA[1][0]); MFMA_(FA[1], FB[1], accA[1][1]);\
    MFMA_(FA[1], FX[0], accX[1][0]); MFMA_(FA[1], FX[1], accX[1][1]);\
    MFMA_(FA[2], FB[0], accA[2][0]); MFMA_(FA[2], FB[1], accA[2][1]);\
    MFMA_(FA[2], FX[0], accX[2][0]); MFMA_(FA[2], FX[1], accX[2][1]);\
    MFMA_(FA[3], FB[0], accA[3][0]); MFMA_(FA[3], FB[1], accA[3][1]);\
    MFMA_(FA[3], FX[0], accX[3][0]); MFMA_(FA[3], FX[1], accX[3][1]);\
  } while (0)

  LOADF(fa0, fb0, fx0, 0);
  LOADF(fa1, fb1, fx1, 1);
  for (int kt = 0; kt < NKT; kt += 2) {
    MSTEP(fa0, fb0, fx0);
    if (kt + 2 < NKT) LOADF(fa0, fb0, fx0, kt + 2);
    MSTEP(fa1, fb1, fx1);
    if (kt + 3 < NKT) LOADF(fa1, fb1, fx1, kt + 3);
  }

  // epilogue: C/D layout col = lane&15 (h), row = (lane>>4)*4 + j (m)
  #pragma unroll
  for (int ni = 0; ni < 2; ni++) {
    const int h = h0 + wn*32 + ni*16 + (lane & 15);
    const float bah = ba[h], bxh = bx[h], kl = klam[h];
    #pragma unroll
    for (int mi = 0; mi < 4; mi++) {
      const int mb = m0 + wm*64 + mi*16 + ((lane >> 4) << 2);
      #pragma unroll
      for (int j = 0; j < 4; j++) {
        const int m = mb + j;
        const float ga = accA[mi][ni][j] + bah;
        const float gx = accX[mi][ni][j] + bxh;
        const float rt = 1.0f / (1.0f + __expf(-ga));
        const float it = 1.0f / (1.0f + __expf(-gx));
        const float a  = __expf(kl * rt);
        // x reload from fragment-order xb [R9-verified formula]
        const size_t e = (size_t)((m >> 5) * 32 + (h >> 5)) * 1024
                       + (size_t)(((m >> 4) & 1) * 64 + ((h >> 3) & 3) * 16 + (m & 15)) * 8
                       + (h & 7);
        const float bb = sqrtf(fmaxf(1.0f - a*a, 0.0f)) * (it * (float)xb[e]);
        Aarr[(size_t)m * DDIM + h] = a;                 // a -> d_out (f32)
        Bp[(size_t)m * DDIM + h]   = (bf16)bb;          // full b -> ws (bf16)
      }
    }
  }
#undef LOADF
#undef MSTEP
}

// ---------------- chunked scan: phase 1 (per-chunk summaries) ----------------
__global__ void scan1_kernel(const float* __restrict__ Aarr, const bf16* __restrict__ Bp,
                             float* __restrict__ sA, float* __restrict__ sB) {
  const int ch = blockIdx.x * 256 + threadIdx.x;   // 0..4095 = b*1024 + d
  const int c  = blockIdx.y;                       // chunk
  const int b  = ch >> 10, d = ch & 1023;
  size_t idx = ((size_t)b * SLEN + (size_t)c * CLEN) * DDIM + d;
  float pa = 1.0f, h = 0.0f;
  #pragma unroll 4
  for (int s = 0; s < CLEN; ++s) {
    const float a  = Aarr[idx];
    const float bb = (float)Bp[idx];
    h  = fmaf(a, h, bb);
    pa *= a;
    idx += DDIM;
  }
  sA[c * NCH + ch] = pa;
  sB[c * NCH + ch] = h;
}

// ---------------- phase 2: sequential prefix over chunks ----------------
__global__ void scan2_kernel(const float* __restrict__ sA, const float* __restrict__ sB,
                             float* __restrict__ Hin) {
  const int ch = blockIdx.x * 256 + threadIdx.x;
  float h = 0.0f;
  for (int c = 0; c < NCHUNK; ++c) {
    Hin[c * NCH + ch] = h;
    h = fmaf(sA[c * NCH + ch], h, sB[c * NCH + ch]);
  }
}

// ---------------- phase 3: apply (a lives in y == d_out; in-place) ----------
__global__ void scan3_kernel(const bf16* __restrict__ Bp, const float* __restrict__ Hin,
                             float* __restrict__ y) {
  const int ch = blockIdx.x * 256 + threadIdx.x;
  const int c  = blockIdx.y;
  const int b  = ch >> 10, d = ch & 1023;
  size_t idx = ((size_t)b * SLEN + (size_t)c * CLEN) * DDIM + d;
  float h = Hin[c * NCH + ch];
  #pragma unroll 4
  for (int s = 0; s < CLEN; ++s) {
    const float a  = y[idx];                 // read a (same slot we overwrite)
    h = fmaf(a, h, (float)Bp[idx]);
    y[idx] = h;
    idx += DDIM;
  }
}

extern "C" void kernel_launch(void* const* d_in, const int* in_sizes, int n_in,
                              void* d_out, int out_size, void* d_ws, size_t ws_size,
                              hipStream_t stream) {
  const float* x   = (const float*)d_in[0];
  const float* Wa  = (const float*)d_in[1];
  const float* Wx  = (const float*)d_in[2];
  const float* ba  = (const float*)d_in[3];
  const float* bx  = (const float*)d_in[4];
  const float* Lam = (const float*)d_in[5];
  float* y = (float*)d_out;

  // workspace layout (bytes): total 74,452,992
  if (ws_size < 74452992ULL) return;  // insufficient scratch; fail cleanly
  char* ws = (char*)d_ws;
  bf16*  xb   = (bf16*)(ws);                     // 32 MB: x bf16, frag-order
  bf16*  wab  = (bf16*)(ws + 33554432);          //  2 MB, frag-order
  bf16*  wxb  = (bf16*)(ws + 35651584);          //  2 MB, frag-order
  bf16*  Bp   = (bf16*)(ws + 37748736);          // 32 MB: b (bf16)
  float* klam = (float*)(ws + 71303168);         //  4 KB
  float* sA   = (float*)(ws + 71307264);         //  1 MB
  float* sB   = (float*)(ws + 72355840);         //  1 MB
  float* Hin  = (float*)(ws + 73404416);         //  1 MB
  float* Aarr = y;                               // a lives in d_out, scan3 in-place

  cast_swz_kernel<<<(MROWS/32)*(KDIM/32)*128/256, 256, 0, stream>>>(x,  xb);
  cast_swz_kernel<<<(DDIM/32)*(KDIM/32)*128/256, 256, 0, stream>>>(Wa, wab);
  cast_swz_kernel<<<(DDIM/32)*(KDIM/32)*128/256, 256, 0, stream>>>(Wx, wxb);
  klam_kernel<<<DDIM/256, 256, 0, stream>>>(Lam, klam);

  // 2048 blocks: (M/128) * (N/64) = 128 * 16
  gemm_gates_kernel<<<2048, 256, 0, stream>>>(xb, wab, wxb, ba, bx, klam, Aarr, Bp);

  dim3 sgrid(NCH/256, NCHUNK);
  scan1_kernel<<<sgrid, 256, 0, stream>>>(Aarr, Bp, sA, sB);
  scan2_kernel<<<NCH/256, 256, 0, stream>>>(sA, sB, Hin);
  scan3_kernel<<<sgrid, 256, 0, stream>>>(Bp, Hin, y);
}

// Round 11
// 153.508 us; speedup vs baseline: 1.2268x; 1.2097x over previous
//
#include <hip/hip_runtime.h>
#include <hip/hip_bf16.h>
#include <math.h>

#define BDIM 4
#define SLEN 4096
#define DDIM 1024
#define MROWS (BDIM*SLEN)      // 16384
#define KDIM DDIM              // 1024
#define NCHUNK 64
#define CLEN (SLEN/NCHUNK)     // 64
#define NCH (BDIM*DDIM)        // 4096
#define NKT (KDIM/32)          // 32 K-steps
#define LDSBUF 16384           // one buffer: X 8KB (4 tiles) + Wa 4KB + Wx 4KB

typedef __bf16 bf16;
typedef __bf16 bf16x8 __attribute__((ext_vector_type(8)));
typedef float f32x16 __attribute__((ext_vector_type(16)));

__device__ __forceinline__ void gload_lds16(const void* g, void* l) {
  __builtin_amdgcn_global_load_lds(
      (const __attribute__((address_space(1))) unsigned int*)g,
      (__attribute__((address_space(3))) unsigned int*)l, 16, 0, 0);
}

// ---------------- cast f32 -> bf16 with fragment-order tile swizzle ----------
// [R8-verified] Tile = 32 rows x 32 k (2KB) at [T][KT]. Granule (r, j) stored
// at slot j*32 + r, so a 32x32x16 fragment read = base + lane*16 gives
// row = lane&31, k-granule = lane>>5. Reads coalesced; writes permute in 2KB.
__global__ void cast_swz_kernel(const float* __restrict__ in, bf16* __restrict__ out) {
  const int gid  = blockIdx.x * 256 + threadIdx.x;
  const int tile = gid >> 7, local = gid & 127;
  const int j = local & 3, r = local >> 2;     // coalesced read assignment
  const int T = tile >> 5, KT = tile & 31;
  const float4* src = (const float4*)(in + (size_t)(T*32 + r) * KDIM + KT*32 + j*8);
  float4 v0 = src[0], v1 = src[1];
  bf16x8 o;
  o[0] = (bf16)v0.x; o[1] = (bf16)v0.y; o[2] = (bf16)v0.z; o[3] = (bf16)v0.w;
  o[4] = (bf16)v1.x; o[5] = (bf16)v1.y; o[6] = (bf16)v1.z; o[7] = (bf16)v1.w;
  ((bf16x8*)out)[(size_t)tile * 128 + j*32 + r] = o;   // fragment-order slot
}

// ---------------- klam[h] = -C * softplus(-Lam[h]) ----------------
__global__ void klam_kernel(const float* __restrict__ Lam, float* __restrict__ klam) {
  int h = blockIdx.x * blockDim.x + threadIdx.x;
  if (h < DDIM) klam[h] = -8.0f * log1pf(__expf(-Lam[h]));
}

// ---------------- dual-weight GEMM + gate epilogue + FUSED chunk summary ----
// [R8 main loop verbatim: 121us, 0 conflicts] Block 128(M) x 64(N), BK=32,
// 4 waves of 64x32-dual, 32x32x16 MFMA, 3 LDS buffers, vmcnt(4) counted waits.
// Epilogue: a = exp(klam*sig(Ga)), b = sqrt(1-a^2)*sig(Gx)*x; writes a (f32,
// d_out), b (bf16, ws), AND the per-chunk scan summary (sA = prod a,
// sB = h with h0=0) — each lane owns ONE column, a wave's 64 rows = 1 chunk,
// so the summary is 8 in-thread segment maps + shfl_xor(32) + 15 composes.
__global__ __launch_bounds__(256, 3) void gemm_gates_kernel(
    const bf16* __restrict__ xb, const bf16* __restrict__ wab, const bf16* __restrict__ wxb,
    const float* __restrict__ ba, const float* __restrict__ bx,
    const float* __restrict__ klam, float* __restrict__ Aarr, bf16* __restrict__ Bp,
    float* __restrict__ sAo, float* __restrict__ sBo)
{
  __shared__ char smem[3*LDSBUF];   // 48 KB

  const int tid  = threadIdx.x;
  const int wave = tid >> 6, lane = tid & 63;
  const int wm = wave >> 1, wn = wave & 1;       // M split 2x64, N split 2x32

  // XCD-bijective swizzle: 2048 blocks, 8 XCDs, 256 each.
  const int orig  = blockIdx.x;
  const int newid = (orig & 7) * 256 + (orig >> 3);
  const int m0 = (newid >> 4) * 128;
  const int h0 = (newid & 15) * 64;

  f32x16 accA0 = (f32x16)0.0f, accA1 = (f32x16)0.0f;
  f32x16 accX0 = (f32x16)0.0f, accX1 = (f32x16)0.0f;

  const int Tb = m0 >> 5;           // first of 4 X row-tiles
  const int Ht = h0 >> 5;           // first of 2 W row-tiles
  const bf16* xsrc0 = xb  + (size_t)(Tb + (tid >> 7)) * 32768 + (tid & 127) * 8;
  const bf16* xsrc1 = xsrc0 + 2 * 32768;
  const bf16* wsrcA = wab + (size_t)(Ht + (tid >> 7)) * 32768 + (tid & 127) * 8;
  const bf16* wsrcX = wxb + (size_t)(Ht + (tid >> 7)) * 32768 + (tid & 127) * 8;

  auto STAGE = [&](int KT, char* nb) {
    gload_lds16(xsrc0 + KT*1024, nb + tid*16);            // X tiles 0,1
    gload_lds16(xsrc1 + KT*1024, nb + 4096  + tid*16);    // X tiles 2,3
    gload_lds16(wsrcA + KT*1024, nb + 8192  + tid*16);    // Wa tiles 0,1
    gload_lds16(wsrcX + KT*1024, nb + 12288 + tid*16);    // Wx tiles 0,1
  };

  const int awoff  = wm*4096  + lane*16;            // A: tiles wm*2, wm*2+1
  const int bwoffA = 8192  + wn*2048 + lane*16;     // Wa tile wn
  const int bwoffX = 12288 + wn*2048 + lane*16;     // Wx tile wn

  char* b0 = smem;
  char* b1 = smem + LDSBUF;
  char* b2 = smem + 2*LDSBUF;

  STAGE(0, b0);
  STAGE(1, b1);

  char *pc = b0, *pn = b1, *ps = b2;
  for (int kt = 0; kt < NKT; ++kt) {
    if (kt == NKT - 1) { asm volatile("s_waitcnt vmcnt(0)" ::: "memory"); }
    else               { asm volatile("s_waitcnt vmcnt(4)" ::: "memory"); }
    __builtin_amdgcn_s_barrier();
    __builtin_amdgcn_sched_barrier(0);

    if (kt + 2 < NKT) STAGE(kt + 2, ps);

    bf16x8 a00 = *(const bf16x8*)(pc + awoff);            // mt0, k 0..16
    bf16x8 a01 = *(const bf16x8*)(pc + awoff + 1024);     // mt0, k 16..32
    bf16x8 a10 = *(const bf16x8*)(pc + awoff + 2048);     // mt1, k 0..16
    bf16x8 a11 = *(const bf16x8*)(pc + awoff + 3072);     // mt1, k 16..32
    bf16x8 ba0 = *(const bf16x8*)(pc + bwoffA);
    bf16x8 ba1 = *(const bf16x8*)(pc + bwoffA + 1024);
    bf16x8 bx0 = *(const bf16x8*)(pc + bwoffX);
    bf16x8 bx1 = *(const bf16x8*)(pc + bwoffX + 1024);

    __builtin_amdgcn_s_setprio(1);
    accA0 = __builtin_amdgcn_mfma_f32_32x32x16_bf16(a00, ba0, accA0, 0, 0, 0);
    accA1 = __builtin_amdgcn_mfma_f32_32x32x16_bf16(a10, ba0, accA1, 0, 0, 0);
    accX0 = __builtin_amdgcn_mfma_f32_32x32x16_bf16(a00, bx0, accX0, 0, 0, 0);
    accX1 = __builtin_amdgcn_mfma_f32_32x32x16_bf16(a10, bx0, accX1, 0, 0, 0);
    accA0 = __builtin_amdgcn_mfma_f32_32x32x16_bf16(a01, ba1, accA0, 0, 0, 0);
    accA1 = __builtin_amdgcn_mfma_f32_32x32x16_bf16(a11, ba1, accA1, 0, 0, 0);
    accX0 = __builtin_amdgcn_mfma_f32_32x32x16_bf16(a01, bx1, accX0, 0, 0, 0);
    accX1 = __builtin_amdgcn_mfma_f32_32x32x16_bf16(a11, bx1, accX1, 0, 0, 0);
    __builtin_amdgcn_s_setprio(0);

    char* tmp = pc; pc = pn; pn = ps; ps = tmp;
  }

  // ---- epilogue ----
  // C/D layout (32x32): col = lane&31, row = (q&3) + 8*(q>>2) + 4*(lane>>5)
  const int colh = h0 + wn*32 + (lane & 31);
  const int hi   = lane >> 5;
  const float bah = ba[colh], bxh = bx[colh], kl = klam[colh];
  // x reload from fragment-order xb [R8-verified]
  const size_t xh = (size_t)(colh >> 5) * 1024 + ((colh >> 3) & 3) * 256 + (colh & 7);

  // segment maps: P/S over 4 consecutive rows (g-group), per mt and this hi.
  float P[2][4], S[2][4];
  #pragma unroll
  for (int mt = 0; mt < 2; ++mt) {
    const int mbase = m0 + wm*64 + mt*32;
    const size_t xtb = (size_t)(mbase >> 5) * 32768 + xh;
    const f32x16 aA = mt ? accA1 : accA0;
    const f32x16 aX = mt ? accX1 : accX0;
    #pragma unroll
    for (int g = 0; g < 4; ++g) {
      float Pg = 1.0f, Sg = 0.0f;
      #pragma unroll
      for (int jj = 0; jj < 4; ++jj) {
        const int q   = g*4 + jj;
        const int row = jj + 8*g + 4*hi;          // rows increase with jj
        const int m   = mbase + row;
        const float ga = aA[q] + bah;
        const float gx = aX[q] + bxh;
        const float rt = 1.0f / (1.0f + __expf(-ga));
        const float it = 1.0f / (1.0f + __expf(-gx));
        const float a  = __expf(kl * rt);
        const float xv = (float)xb[xtb + (size_t)row * 8];
        const float bb = sqrtf(fmaxf(1.0f - a*a, 0.0f)) * (it * xv);
        Aarr[(size_t)m * DDIM + colh] = a;        // a -> d_out (f32)
        Bp[(size_t)m * DDIM + colh]   = (bf16)bb; // b -> ws (bf16)
        Sg = fmaf(a, Sg, bb);                     // S = (((b0)a1+b1)a2+b2)a3+b3
        Pg *= a;
      }
      P[mt][g] = Pg; S[mt][g] = Sg;
    }
  }

  // compose the 16 segments in row order: sigma = mt*8 + g*2 + hi'
  float Pc = 1.0f, Sc = 0.0f;
  #pragma unroll
  for (int mt = 0; mt < 2; ++mt) {
    #pragma unroll
    for (int g = 0; g < 4; ++g) {
      const float pm = P[mt][g], sm = S[mt][g];
      const float pp = __shfl_xor(pm, 32);
      const float sp = __shfl_xor(sm, 32);
      const float p0 = hi ? pp : pm, s0 = hi ? sp : sm;   // hi'=0 first
      const float p1 = hi ? pm : pp, s1 = hi ? sm : sp;   // then hi'=1
      Sc = fmaf(p0, Sc, s0); Pc *= p0;
      Sc = fmaf(p1, Sc, s1); Pc *= p1;
    }
  }
  if (hi == 0) {
    const int mb0  = m0 + wm*64;          // chunk start (64-aligned)
    const int bidx = mb0 >> 12;           // batch
    const int c    = (mb0 & (SLEN-1)) >> 6;  // chunk within sequence
    sAo[(size_t)c * NCH + bidx*1024 + colh] = Pc;
    sBo[(size_t)c * NCH + bidx*1024 + colh] = Sc;
  }
}

// ---------------- phase 2: sequential prefix over chunks ----------------
__global__ void scan2_kernel(const float* __restrict__ sA, const float* __restrict__ sB,
                             float* __restrict__ Hin) {
  const int ch = blockIdx.x * 256 + threadIdx.x;
  float h = 0.0f;
  for (int c = 0; c < NCHUNK; ++c) {
    Hin[c * NCH + ch] = h;
    h = fmaf(sA[c * NCH + ch], h, sB[c * NCH + ch]);
  }
}

// ---------------- phase 3: apply (a lives in y == d_out; in-place) ----------
__global__ void scan3_kernel(const bf16* __restrict__ Bp, const float* __restrict__ Hin,
                             float* __restrict__ y) {
  const int ch = blockIdx.x * 256 + threadIdx.x;
  const int c  = blockIdx.y;
  const int b  = ch >> 10, d = ch & 1023;
  size_t idx = ((size_t)b * SLEN + (size_t)c * CLEN) * DDIM + d;
  float h = Hin[c * NCH + ch];
  #pragma unroll 4
  for (int s = 0; s < CLEN; ++s) {
    const float a = y[idx];                 // read a (same slot we overwrite)
    h = fmaf(a, h, (float)Bp[idx]);
    y[idx] = h;
    idx += DDIM;
  }
}

extern "C" void kernel_launch(void* const* d_in, const int* in_sizes, int n_in,
                              void* d_out, int out_size, void* d_ws, size_t ws_size,
                              hipStream_t stream) {
  const float* x   = (const float*)d_in[0];
  const float* Wa  = (const float*)d_in[1];
  const float* Wx  = (const float*)d_in[2];
  const float* ba  = (const float*)d_in[3];
  const float* bx  = (const float*)d_in[4];
  const float* Lam = (const float*)d_in[5];
  float* y = (float*)d_out;

  // workspace layout (bytes): total 74,452,992
  if (ws_size < 74452992ULL) return;  // insufficient scratch; fail cleanly
  char* ws = (char*)d_ws;
  bf16*  xb   = (bf16*)(ws);                     // 32 MB: x bf16, frag-order
  bf16*  wab  = (bf16*)(ws + 33554432);          //  2 MB, frag-order
  bf16*  wxb  = (bf16*)(ws + 35651584);          //  2 MB, frag-order
  bf16*  Bp   = (bf16*)(ws + 37748736);          // 32 MB: b (bf16)
  float* klam = (float*)(ws + 71303168);         //  4 KB
  float* sA   = (float*)(ws + 71307264);         //  1 MB
  float* sB   = (float*)(ws + 72355840);         //  1 MB
  float* Hin  = (float*)(ws + 73404416);         //  1 MB
  float* Aarr = y;                               // a lives in d_out, scan3 in-place

  cast_swz_kernel<<<(MROWS/32)*(KDIM/32)*128/256, 256, 0, stream>>>(x,  xb);
  cast_swz_kernel<<<(DDIM/32)*(KDIM/32)*128/256, 256, 0, stream>>>(Wa, wab);
  cast_swz_kernel<<<(DDIM/32)*(KDIM/32)*128/256, 256, 0, stream>>>(Wx, wxb);
  klam_kernel<<<DDIM/256, 256, 0, stream>>>(Lam, klam);

  // 2048 blocks: (M/128) * (N/64) = 128 * 16
  gemm_gates_kernel<<<2048, 256, 0, stream>>>(xb, wab, wxb, ba, bx, klam,
                                              Aarr, Bp, sA, sB);

  scan2_kernel<<<NCH/256, 256, 0, stream>>>(sA, sB, Hin);
  dim3 sgrid(NCH/256, NCHUNK);
  scan3_kernel<<<sgrid, 256, 0, stream>>>(Bp, Hin, y);
}

// Round 12
// 149.009 us; speedup vs baseline: 1.2639x; 1.0302x over previous
//
#include <hip/hip_runtime.h>
#include <hip/hip_bf16.h>
#include <math.h>

#define BDIM 4
#define SLEN 4096
#define DDIM 1024
#define MROWS (BDIM*SLEN)      // 16384
#define KDIM DDIM              // 1024
#define NCHUNK 64
#define CLEN (SLEN/NCHUNK)     // 64
#define NCH (BDIM*DDIM)        // 4096
#define NKT (KDIM/32)          // 32 K-steps
#define LDSBUF 16384           // one buffer: X 8KB (4 tiles) + Wa 4KB + Wx 4KB

typedef __bf16 bf16;
typedef __bf16 bf16x8 __attribute__((ext_vector_type(8)));
typedef float f32x16 __attribute__((ext_vector_type(16)));

__device__ __forceinline__ void gload_lds16(const void* g, void* l) {
  __builtin_amdgcn_global_load_lds(
      (const __attribute__((address_space(1))) unsigned int*)g,
      (__attribute__((address_space(3))) unsigned int*)l, 16, 0, 0);
}

// ---------------- cast f32 -> bf16 with fragment-order tile swizzle ----------
// [R8-verified] Tile = 32 rows x 32 k (2KB) at [T][KT]. Granule (r, j) stored
// at slot j*32 + r, so a 32x32x16 fragment read = base + lane*16 gives
// row = lane&31, k-granule = lane>>5. Reads coalesced; writes permute in 2KB.
__global__ void cast_swz_kernel(const float* __restrict__ in, bf16* __restrict__ out) {
  const int gid  = blockIdx.x * 256 + threadIdx.x;
  const int tile = gid >> 7, local = gid & 127;
  const int j = local & 3, r = local >> 2;     // coalesced read assignment
  const int T = tile >> 5, KT = tile & 31;
  const float4* src = (const float4*)(in + (size_t)(T*32 + r) * KDIM + KT*32 + j*8);
  float4 v0 = src[0], v1 = src[1];
  bf16x8 o;
  o[0] = (bf16)v0.x; o[1] = (bf16)v0.y; o[2] = (bf16)v0.z; o[3] = (bf16)v0.w;
  o[4] = (bf16)v1.x; o[5] = (bf16)v1.y; o[6] = (bf16)v1.z; o[7] = (bf16)v1.w;
  ((bf16x8*)out)[(size_t)tile * 128 + j*32 + r] = o;   // fragment-order slot
}

// ---------------- klam[h] = -C * softplus(-Lam[h]) ----------------
__global__ void klam_kernel(const float* __restrict__ Lam, float* __restrict__ klam) {
  int h = blockIdx.x * blockDim.x + threadIdx.x;
  if (h < DDIM) klam[h] = -8.0f * log1pf(__expf(-Lam[h]));
}

// ---------------- dual-weight GEMM + gate epilogue + FUSED chunk summary ----
// [R11 + m201-style phase ordering] Block 128(M) x 64(N), BK=32, 4 waves of
// 64x32-dual, 32x32x16 MFMA, 3 LDS buffers, 2 tiles in flight.
// K-step: {8 ds_read(t) ; STAGE(t+2)} -> barrier (absorbs ds latency) ->
// lgkmcnt(0) (cheap) -> 8 MFMA -> vmcnt(4) -> barrier.
__global__ __launch_bounds__(256, 3) void gemm_gates_kernel(
    const bf16* __restrict__ xb, const bf16* __restrict__ wab, const bf16* __restrict__ wxb,
    const float* __restrict__ ba, const float* __restrict__ bx,
    const float* __restrict__ klam, float* __restrict__ Aarr, bf16* __restrict__ Bp,
    float* __restrict__ sAo, float* __restrict__ sBo)
{
  __shared__ char smem[3*LDSBUF];   // 48 KB

  const int tid  = threadIdx.x;
  const int wave = tid >> 6, lane = tid & 63;
  const int wm = wave >> 1, wn = wave & 1;       // M split 2x64, N split 2x32

  // XCD-bijective swizzle: 2048 blocks, 8 XCDs, 256 each.
  const int orig  = blockIdx.x;
  const int newid = (orig & 7) * 256 + (orig >> 3);
  const int m0 = (newid >> 4) * 128;
  const int h0 = (newid & 15) * 64;

  f32x16 accA0 = (f32x16)0.0f, accA1 = (f32x16)0.0f;
  f32x16 accX0 = (f32x16)0.0f, accX1 = (f32x16)0.0f;

  const int Tb = m0 >> 5;           // first of 4 X row-tiles
  const int Ht = h0 >> 5;           // first of 2 W row-tiles
  const bf16* xsrc0 = xb  + (size_t)(Tb + (tid >> 7)) * 32768 + (tid & 127) * 8;
  const bf16* xsrc1 = xsrc0 + 2 * 32768;
  const bf16* wsrcA = wab + (size_t)(Ht + (tid >> 7)) * 32768 + (tid & 127) * 8;
  const bf16* wsrcX = wxb + (size_t)(Ht + (tid >> 7)) * 32768 + (tid & 127) * 8;

  auto STAGE = [&](int KT, char* nb) {
    gload_lds16(xsrc0 + KT*1024, nb + tid*16);            // X tiles 0,1
    gload_lds16(xsrc1 + KT*1024, nb + 4096  + tid*16);    // X tiles 2,3
    gload_lds16(wsrcA + KT*1024, nb + 8192  + tid*16);    // Wa tiles 0,1
    gload_lds16(wsrcX + KT*1024, nb + 12288 + tid*16);    // Wx tiles 0,1
  };

  const int awoff  = wm*4096  + lane*16;            // A: tiles wm*2, wm*2+1
  const int bwoffA = 8192  + wn*2048 + lane*16;     // Wa tile wn
  const int bwoffX = 12288 + wn*2048 + lane*16;     // Wx tile wn

  char* b0 = smem;
  char* b1 = smem + LDSBUF;
  char* b2 = smem + 2*LDSBUF;

  STAGE(0, b0);
  STAGE(1, b1);
  asm volatile("s_waitcnt vmcnt(4)" ::: "memory");   // tile 0 landed
  __builtin_amdgcn_s_barrier();

  char *pc = b0, *pn = b1, *ps = b2;
  for (int kt = 0; kt < NKT; ++kt) {
    // ---- phase 1: issue ds_reads for tile kt, then prefetch tile kt+2 ----
    bf16x8 a00 = *(const bf16x8*)(pc + awoff);            // mt0, k 0..16
    bf16x8 a01 = *(const bf16x8*)(pc + awoff + 1024);     // mt0, k 16..32
    bf16x8 a10 = *(const bf16x8*)(pc + awoff + 2048);     // mt1, k 0..16
    bf16x8 a11 = *(const bf16x8*)(pc + awoff + 3072);     // mt1, k 16..32
    bf16x8 ba0 = *(const bf16x8*)(pc + bwoffA);
    bf16x8 ba1 = *(const bf16x8*)(pc + bwoffA + 1024);
    bf16x8 bx0 = *(const bf16x8*)(pc + bwoffX);
    bf16x8 bx1 = *(const bf16x8*)(pc + bwoffX + 1024);
    __builtin_amdgcn_sched_barrier(0);                 // pin ds_reads here

    if (kt + 2 < NKT) STAGE(kt + 2, ps);

    __builtin_amdgcn_s_barrier();                      // rendezvous absorbs ds latency
    asm volatile("s_waitcnt lgkmcnt(0)" ::: "memory"); // ~free now
    __builtin_amdgcn_sched_barrier(0);                 // rule #18: no MFMA hoist

    __builtin_amdgcn_s_setprio(1);
    accA0 = __builtin_amdgcn_mfma_f32_32x32x16_bf16(a00, ba0, accA0, 0, 0, 0);
    accA1 = __builtin_amdgcn_mfma_f32_32x32x16_bf16(a10, ba0, accA1, 0, 0, 0);
    accX0 = __builtin_amdgcn_mfma_f32_32x32x16_bf16(a00, bx0, accX0, 0, 0, 0);
    accX1 = __builtin_amdgcn_mfma_f32_32x32x16_bf16(a10, bx0, accX1, 0, 0, 0);
    accA0 = __builtin_amdgcn_mfma_f32_32x32x16_bf16(a01, ba1, accA0, 0, 0, 0);
    accA1 = __builtin_amdgcn_mfma_f32_32x32x16_bf16(a11, ba1, accA1, 0, 0, 0);
    accX0 = __builtin_amdgcn_mfma_f32_32x32x16_bf16(a01, bx1, accX0, 0, 0, 0);
    accX1 = __builtin_amdgcn_mfma_f32_32x32x16_bf16(a11, bx1, accX1, 0, 0, 0);
    __builtin_amdgcn_s_setprio(0);

    // ---- end-of-step: ensure tile kt+1 fully landed for next step's reads ----
    if (kt + 2 < NKT)      { asm volatile("s_waitcnt vmcnt(4)" ::: "memory"); }
    else if (kt + 1 < NKT) { asm volatile("s_waitcnt vmcnt(0)" ::: "memory"); }
    if (kt + 1 < NKT) __builtin_amdgcn_s_barrier();

    char* tmp = pc; pc = pn; pn = ps; ps = tmp;
  }

  // ---- epilogue ----
  // C/D layout (32x32): col = lane&31, row = (q&3) + 8*(q>>2) + 4*(lane>>5)
  const int colh = h0 + wn*32 + (lane & 31);
  const int hi   = lane >> 5;
  const float bah = ba[colh], bxh = bx[colh], kl = klam[colh];
  // x reload from fragment-order xb [R8-verified]
  const size_t xh = (size_t)(colh >> 5) * 1024 + ((colh >> 3) & 3) * 256 + (colh & 7);

  // segment maps: P/S over 4 consecutive rows (g-group), per mt and this hi.
  float P[2][4], S[2][4];
  #pragma unroll
  for (int mt = 0; mt < 2; ++mt) {
    const int mbase = m0 + wm*64 + mt*32;
    const size_t xtb = (size_t)(mbase >> 5) * 32768 + xh;
    const f32x16 aA = mt ? accA1 : accA0;
    const f32x16 aX = mt ? accX1 : accX0;
    #pragma unroll
    for (int g = 0; g < 4; ++g) {
      float Pg = 1.0f, Sg = 0.0f;
      #pragma unroll
      for (int jj = 0; jj < 4; ++jj) {
        const int q   = g*4 + jj;
        const int row = jj + 8*g + 4*hi;          // rows increase with jj
        const int m   = mbase + row;
        const float ga = aA[q] + bah;
        const float gx = aX[q] + bxh;
        const float rt = 1.0f / (1.0f + __expf(-ga));
        const float it = 1.0f / (1.0f + __expf(-gx));
        const float a  = __expf(kl * rt);
        const float xv = (float)xb[xtb + (size_t)row * 8];
        const float bb = sqrtf(fmaxf(1.0f - a*a, 0.0f)) * (it * xv);
        Aarr[(size_t)m * DDIM + colh] = a;        // a -> d_out (f32)
        Bp[(size_t)m * DDIM + colh]   = (bf16)bb; // b -> ws (bf16)
        Sg = fmaf(a, Sg, bb);                     // S = (((b0)a1+b1)a2+b2)a3+b3
        Pg *= a;
      }
      P[mt][g] = Pg; S[mt][g] = Sg;
    }
  }

  // compose the 16 segments in row order: sigma = mt*8 + g*2 + hi'
  float Pc = 1.0f, Sc = 0.0f;
  #pragma unroll
  for (int mt = 0; mt < 2; ++mt) {
    #pragma unroll
    for (int g = 0; g < 4; ++g) {
      const float pm = P[mt][g], sm = S[mt][g];
      const float pp = __shfl_xor(pm, 32);
      const float sp = __shfl_xor(sm, 32);
      const float p0 = hi ? pp : pm, s0 = hi ? sp : sm;   // hi'=0 first
      const float p1 = hi ? pm : pp, s1 = hi ? sm : sp;   // then hi'=1
      Sc = fmaf(p0, Sc, s0); Pc *= p0;
      Sc = fmaf(p1, Sc, s1); Pc *= p1;
    }
  }
  if (hi == 0) {
    const int mb0  = m0 + wm*64;          // chunk start (64-aligned)
    const int bidx = mb0 >> 12;           // batch
    const int c    = (mb0 & (SLEN-1)) >> 6;  // chunk within sequence
    sAo[(size_t)c * NCH + bidx*1024 + colh] = Pc;
    sBo[(size_t)c * NCH + bidx*1024 + colh] = Sc;
  }
}

// ---------------- phase 2: sequential prefix over chunks ----------------
__global__ void scan2_kernel(const float* __restrict__ sA, const float* __restrict__ sB,
                             float* __restrict__ Hin) {
  const int ch = blockIdx.x * 256 + threadIdx.x;
  float h = 0.0f;
  for (int c = 0; c < NCHUNK; ++c) {
    Hin[c * NCH + ch] = h;
    h = fmaf(sA[c * NCH + ch], h, sB[c * NCH + ch]);
  }
}

// ---------------- phase 3: apply (a lives in y == d_out; in-place) ----------
__global__ void scan3_kernel(const bf16* __restrict__ Bp, const float* __restrict__ Hin,
                             float* __restrict__ y) {
  const int ch = blockIdx.x * 256 + threadIdx.x;
  const int c  = blockIdx.y;
  const int b  = ch >> 10, d = ch & 1023;
  size_t idx = ((size_t)b * SLEN + (size_t)c * CLEN) * DDIM + d;
  float h = Hin[c * NCH + ch];
  #pragma unroll 4
  for (int s = 0; s < CLEN; ++s) {
    const float a = y[idx];                 // read a (same slot we overwrite)
    h = fmaf(a, h, (float)Bp[idx]);
    y[idx] = h;
    idx += DDIM;
  }
}

extern "C" void kernel_launch(void* const* d_in, const int* in_sizes, int n_in,
                              void* d_out, int out_size, void* d_ws, size_t ws_size,
                              hipStream_t stream) {
  const float* x   = (const float*)d_in[0];
  const float* Wa  = (const float*)d_in[1];
  const float* Wx  = (const float*)d_in[2];
  const float* ba  = (const float*)d_in[3];
  const float* bx  = (const float*)d_in[4];
  const float* Lam = (const float*)d_in[5];
  float* y = (float*)d_out;

  // workspace layout (bytes): total 74,452,992
  if (ws_size < 74452992ULL) return;  // insufficient scratch; fail cleanly
  char* ws = (char*)d_ws;
  bf16*  xb   = (bf16*)(ws);                     // 32 MB: x bf16, frag-order
  bf16*  wab  = (bf16*)(ws + 33554432);          //  2 MB, frag-order
  bf16*  wxb  = (bf16*)(ws + 35651584);          //  2 MB, frag-order
  bf16*  Bp   = (bf16*)(ws + 37748736);          // 32 MB: b (bf16)
  float* klam = (float*)(ws + 71303168);         //  4 KB
  float* sA   = (float*)(ws + 71307264);         //  1 MB
  float* sB   = (float*)(ws + 72355840);         //  1 MB
  float* Hin  = (float*)(ws + 73404416);         //  1 MB
  float* Aarr = y;                               // a lives in d_out, scan3 in-place

  cast_swz_kernel<<<(MROWS/32)*(KDIM/32)*128/256, 256, 0, stream>>>(x,  xb);
  cast_swz_kernel<<<(DDIM/32)*(KDIM/32)*128/256, 256, 0, stream>>>(Wa, wab);
  cast_swz_kernel<<<(DDIM/32)*(KDIM/32)*128/256, 256, 0, stream>>>(Wx, wxb);
  klam_kernel<<<DDIM/256, 256, 0, stream>>>(Lam, klam);

  // 2048 blocks: (M/128) * (N/64) = 128 * 16
  gemm_gates_kernel<<<2048, 256, 0, stream>>>(xb, wab, wxb, ba, bx, klam,
                                              Aarr, Bp, sA, sB);

  scan2_kernel<<<NCH/256, 256, 0, stream>>>(sA, sB, Hin);
  dim3 sgrid(NCH/256, NCHUNK);
  scan3_kernel<<<sgrid, 256, 0, stream>>>(Bp, Hin, y);
}